// Round 20
// baseline (89.697 us; speedup 1.0000x reference)
//
#include <hip/hip_runtime.h>

#define N_NODES 50000
#define N_EDGES 800000
#define D 64
#define NBUCK 782            // ceil(50000/64) buckets of 64 dst nodes
#define BINBLK 512           // standalone bin blocks (2 per CU, 8 waves)
#define EPB 1563             // edges per bin block (512*1563 = 800256 >= E)
#define ECHUNK 7             // ceil(1563/256)
#define GEMMBLK ((N_NODES + 15) / 16)   // 3125 gemm tiles, 16 rows each
#define CAP 1536             // bucket capacity (mean 1024 + 16 sigma)
#define FIXSCALE 4194304.0f  // 2^22 fixed-point for weighted degree

// ---------------- helpers ----------------

__device__ inline unsigned short f2bf(float f) {
    unsigned u = __float_as_uint(f);
    unsigned r = (u + 0x7FFFu + ((u >> 16) & 1u)) >> 16;   // RNE
    return (unsigned short)r;
}
__device__ inline float bf2f(unsigned short h) {
    return __uint_as_float(((unsigned)h) << 16);
}
__device__ inline int wave_incl_scan(int v, int lane) {
#pragma unroll
    for (int off = 1; off < 64; off <<= 1) {
        int n = __shfl_up(v, off, 64);
        if (lane >= off) v += n;
    }
    return v;
}

// ---------------- kernels ----------------

__global__ void k_zero(int* __restrict__ gcur) {
    int i = blockIdx.x * blockDim.x + threadIdx.x;
    if (i < NBUCK) gcur[i] = 0;
}

// standalone bin: register-stage edges, count in LDS, reserve via global
// atomic, scatter from registers (R16's proven bin path)
__global__ __launch_bounds__(256) void k_bin(
        const int* __restrict__ src, const int* __restrict__ dst,
        const float* __restrict__ ew,
        int* __restrict__ gcur, unsigned long long* __restrict__ binned) {
    __shared__ int lh[NBUCK];
    int t = threadIdx.x;
    int rd[ECHUNK]; int rs[ECHUNK]; float rw[ECHUNK];
    for (int i = t; i < NBUCK; i += 256) lh[i] = 0;
    __syncthreads();
    int base = blockIdx.x * EPB;
#pragma unroll
    for (int i = 0; i < ECHUNK; ++i) {          // pass 1: load + count
        int k = i * 256 + t;
        rd[i] = -1;
        if (k < EPB) {
            int e = base + k;
            if (e < N_EDGES) {
                rd[i] = dst[e];
                rs[i] = src[e];
                rw[i] = ew[e];
                atomicAdd(&lh[rd[i] >> 6], 1);
            }
        }
    }
    __syncthreads();
    for (int i = t; i < NBUCK; i += 256) {
        int c = lh[i];
        lh[i] = (c > 0) ? atomicAdd(&gcur[i], c) : 0;   // block's run base
    }
    __syncthreads();
#pragma unroll
    for (int i = 0; i < ECHUNK; ++i) {          // pass 2: scatter from regs
        if (rd[i] >= 0) {
            int bkt = rd[i] >> 6;
            int pos = atomicAdd(&lh[bkt], 1);
            if (pos < CAP)
                binned[(size_t)bkt * CAP + pos] =
                    ((unsigned long long)__float_as_uint(rw[i]) << 32)
                  | ((unsigned)rs[i] << 16) | (unsigned)rd[i];
        }
    }
}

// Fused: blocks [0,NBUCK) counting-sort buckets to per-node CSR + dinv + rc;
// blocks [NBUCK,..) compute hb = bf16(x @ W). The two legs are independent.
union ShU {
    struct { unsigned long long stage[CAP];
             unsigned long long cw[64]; int off2[64]; } so;   // 12.8 KB
    struct { float Ws[D][D]; float Xs[4][D]; } gm;            // 17.4 KB
};
__global__ __launch_bounds__(256) void k_sortgemm(
        const unsigned long long* __restrict__ binned,
        const int* __restrict__ gcur,
        unsigned* __restrict__ csr, unsigned* __restrict__ rc,
        float* __restrict__ dinv,
        const float* __restrict__ x, const float* __restrict__ W,
        unsigned short* __restrict__ hb) {
    __shared__ ShU sh;
    int t = threadIdx.x;
    int bid = blockIdx.x;
    if (bid < NBUCK) {
        unsigned long long* stage = sh.so.stage;
        unsigned long long* cw = sh.so.cw;
        int* off2 = sh.so.off2;
        if (t < 64) cw[t] = 0ULL;
        __syncthreads();
        int b = bid;
        size_t beg = (size_t)b * CAP;
        int len = min(gcur[b], CAP);
        for (int k = t; k < len; k += 256) {
            unsigned long long p = binned[beg + k];
            stage[k] = p;
            int dl = (int)(p & 63);
            float w = __uint_as_float((unsigned)(p >> 32));
            atomicAdd(&cw[dl],
                      (1ULL << 40) | (unsigned long long)__float2uint_rn(w * FIXSCALE));
        }
        __syncthreads();
        if (t < 64) {
            int c = (int)(cw[t] >> 40);
            float wfix = (float)(cw[t] & ((1ULL << 40) - 1ULL));
            int inc = wave_incl_scan(c, t);
            int excl = inc - c;
            off2[t] = excl;
            int node = b * 64 + t;
            if (node < N_NODES) {
                rc[node] = ((unsigned)c << 12) | (unsigned)excl;
                dinv[node] = rsqrtf(1.0f + wfix * (1.0f / FIXSCALE));
            }
        }
        __syncthreads();
        for (int k = t; k < len; k += 256) {
            unsigned long long p = stage[k];
            int dl = (int)(p & 63);
            int r = atomicAdd(&off2[dl], 1);
            unsigned short ewb = f2bf(__uint_as_float((unsigned)(p >> 32)));
            csr[beg + r] = ((unsigned)ewb << 16) | (unsigned)((p >> 16) & 0xffffu);
        }
    } else {
        float (*Ws)[D] = sh.gm.Ws;
        float (*Xs)[D] = sh.gm.Xs;
        for (int k = t; k < D * D; k += 256) Ws[k / D][k % D] = W[k];
        int base = (bid - NBUCK) * 16;
        int r = t >> 6, c = t & 63;
        for (int g = 0; g < 4; ++g) {
            int row = base + g * 4 + r;
            __syncthreads();   // covers Ws staging (g=0) and Xs reuse (g>0)
            Xs[r][c] = (row < N_NODES) ? x[(size_t)row * D + c] : 0.0f;
            __syncthreads();
            float acc = 0.0f;
#pragma unroll
            for (int k = 0; k < D; ++k) acc = fmaf(Xs[r][k], Ws[k][c], acc);
            if (row < N_NODES) hb[(size_t)row * D + c] = f2bf(acc);
        }
    }
}

// one wave per node, two 32-lane halves processing alternate edges of each
// pair — control flow is WAVE-UNIFORM (shfl always executed with all lanes
// active; per-lane shfl index jp+half is a legal bpermute).
__global__ void k_aggregate(const unsigned short* __restrict__ hb,
                            const float* __restrict__ dinv,
                            const unsigned* __restrict__ rc,
                            const unsigned* __restrict__ csr,
                            const float* __restrict__ bias,
                            float* __restrict__ out) {
    int node = blockIdx.x * 4 + (threadIdx.x >> 6);
    int lane = threadIdx.x & 63;
    if (node >= N_NODES) return;
    int half = lane >> 5;
    int cl = lane & 31;          // column pair: cols 2cl, 2cl+1
    float di = dinv[node];
    unsigned r = rc[node];
    int cnt = (int)(r >> 12);
    size_t beg = (size_t)(node >> 6) * CAP + (r & 0xFFFu);
    float a0 = 0.0f, a1 = 0.0f, p0 = 0.0f, p1 = 0.0f;
    {   // self-loop term, counted once (half 0 lanes)
        unsigned hd = *(const unsigned*)(hb + (size_t)node * D + 2 * cl);
        float m = (half == 0) ? di : 0.0f;
        a0 = m * bf2f((unsigned short)hd);
        a1 = m * bf2f((unsigned short)(hd >> 16));
    }
    for (int b0 = 0; b0 < cnt; b0 += 64) {
        int n = min(64, cnt - b0);
        int my_src = 0;
        float my_ew = 0.0f;
        if (lane < n) {
            unsigned q = csr[beg + b0 + lane];
            my_src = (int)(q & 0xffffu);
            my_ew = bf2f((unsigned short)(q >> 16)) * dinv[my_src];  // L2-resident
        }
        int jp = 0;
        for (; jp + 3 < n; jp += 4) {        // uniform: pairs (jp, jp+1), (jp+2, jp+3)
            int iA = jp + half, iB = jp + 2 + half;
            int sA = __shfl(my_src, iA, 64);
            float eA = __shfl(my_ew, iA, 64);
            int sB = __shfl(my_src, iB, 64);
            float eB = __shfl(my_ew, iB, 64);
            unsigned hA = *(const unsigned*)(hb + (size_t)sA * D + 2 * cl);
            unsigned hB = *(const unsigned*)(hb + (size_t)sB * D + 2 * cl);
            a0 = fmaf(bf2f((unsigned short)hA), eA, a0);
            a1 = fmaf(bf2f((unsigned short)(hA >> 16)), eA, a1);
            p0 = fmaf(bf2f((unsigned short)hB), eB, p0);
            p1 = fmaf(bf2f((unsigned short)(hB >> 16)), eB, p1);
        }
        for (; jp + 1 < n; jp += 2) {        // uniform: one pair
            int iA = jp + half;
            int sA = __shfl(my_src, iA, 64);
            float eA = __shfl(my_ew, iA, 64);
            unsigned hA = *(const unsigned*)(hb + (size_t)sA * D + 2 * cl);
            a0 = fmaf(bf2f((unsigned short)hA), eA, a0);
            a1 = fmaf(bf2f((unsigned short)(hA >> 16)), eA, a1);
        }
        if (jp < n) {                        // lone last edge: uniform shfl, half0 FMA
            int sA = __shfl(my_src, jp, 64);
            float eA = __shfl(my_ew, jp, 64);
            unsigned hA = *(const unsigned*)(hb + (size_t)sA * D + 2 * cl);
            float m = (half == 0) ? eA : 0.0f;
            a0 = fmaf(bf2f((unsigned short)hA), m, a0);
            a1 = fmaf(bf2f((unsigned short)(hA >> 16)), m, a1);
        }
    }
    a0 += p0; a1 += p1;
    a0 += __shfl_xor(a0, 32, 64);            // combine halves
    a1 += __shfl_xor(a1, 32, 64);
    if (half == 0) {
        float v0 = fmaf(di, a0, bias[2 * cl]);
        float v1 = fmaf(di, a1, bias[2 * cl + 1]);
        float2 o;
        o.x = fmaxf(v0, 0.0f);
        o.y = fmaxf(v1, 0.0f);
        *(float2*)(out + (size_t)node * D + 2 * cl) = o;
    }
}

// ---------------- launch ----------------

extern "C" void kernel_launch(void* const* d_in, const int* in_sizes, int n_in,
                              void* d_out, int out_size, void* d_ws, size_t ws_size,
                              hipStream_t stream) {
    const float* x  = (const float*)d_in[0];
    const int*   ei = (const int*)d_in[1];    // [2, E] row-major, int32
    const float* ew = (const float*)d_in[2];
    const float* W  = (const float*)d_in[3];
    const float* b  = (const float*)d_in[4];
    float* out = (float*)d_out;

    const int* src = ei;
    const int* dst = ei + N_EDGES;

    // workspace layout (8B-aligned first)
    unsigned long long* binned = (unsigned long long*)d_ws;          // NBUCK*CAP u64 (9.6MB)
    unsigned* csr      = (unsigned*)(binned + (size_t)NBUCK * CAP);  // NBUCK*CAP u32 (4.8MB)
    int*   gcur        = (int*)(csr + (size_t)NBUCK * CAP);          // 1024
    unsigned* rc       = (unsigned*)(gcur + 1024);                   // 50048
    float* dinv        = (float*)(rc + 50048);                       // 50048
    unsigned short* hb = (unsigned short*)(dinv + 50048);            // N*D bf16 (6.4MB)

    dim3 blk(256);
    k_zero<<<4, blk, 0, stream>>>(gcur);
    k_bin<<<BINBLK, blk, 0, stream>>>(src, dst, ew, gcur, binned);
    k_sortgemm<<<NBUCK + GEMMBLK, blk, 0, stream>>>(binned, gcur, csr, rc, dinv,
                                                    x, W, hb);
    k_aggregate<<<(N_NODES + 3) / 4, blk, 0, stream>>>(hb, dinv, rc, csr, b, out);
}

// Round 21
// 85.554 us; speedup vs baseline: 1.0484x; 1.0484x over previous
//
#include <hip/hip_runtime.h>

#define N_NODES 50000
#define N_EDGES 800000
#define D 64
#define NBUCK 782            // ceil(50000/64) buckets of 64 dst nodes
#define BINBLK 256           // bin blocks: 256 ranges (runs of ~4 edges kept)
#define EPB 3125             // edges per bin block (256*3125 = 800000)
#define BT 1024              // k_bin_gemm block size (16 waves: 4x bin TLP)
#define ECHUNK 4             // ceil(3125/1024)
#define GEMMBLK64 ((N_NODES + 63) / 64)   // 782 gemm tiles, 64 rows each
#define CAP 1536             // bucket capacity (mean 1024 + 16 sigma)
#define FIXSCALE 4194304.0f  // 2^22 fixed-point for weighted degree

// ---------------- helpers ----------------

__device__ inline unsigned short f2bf(float f) {
    unsigned u = __float_as_uint(f);
    unsigned r = (u + 0x7FFFu + ((u >> 16) & 1u)) >> 16;   // RNE
    return (unsigned short)r;
}
__device__ inline float bf2f(unsigned short h) {
    return __uint_as_float(((unsigned)h) << 16);
}
__device__ inline int wave_incl_scan(int v, int lane) {
#pragma unroll
    for (int off = 1; off < 64; off <<= 1) {
        int n = __shfl_up(v, off, 64);
        if (lane >= off) v += n;
    }
    return v;
}

// ---------------- kernels ----------------

__global__ void k_zero(int* __restrict__ gcur) {
    int i = blockIdx.x * blockDim.x + threadIdx.x;
    if (i < NBUCK) gcur[i] = 0;
}

// Fused, 1024-thread blocks.
// Bin blocks [0,BINBLK): same 3125-edge range as R17 (run length preserved)
// but 16 waves issue the LDS-atomic -> scatter chains (4x TLP).
// Gemm blocks [BINBLK,..): 64 rows per block.
union ShU {
    int lh[NBUCK];                                    // bin: 3.1 KB
    struct { float Ws[D][D]; float Xs[16][D]; } gm;   // 20 KB
};
__global__ __launch_bounds__(BT) void k_bin_gemm(
        const int* __restrict__ src, const int* __restrict__ dst,
        const float* __restrict__ ew,
        int* __restrict__ gcur, unsigned long long* __restrict__ binned,
        const float* __restrict__ x, const float* __restrict__ W,
        unsigned short* __restrict__ hb) {
    __shared__ ShU sh;
    int t = threadIdx.x;
    int bid = blockIdx.x;
    if (bid < BINBLK) {
        int rd[ECHUNK]; int rs[ECHUNK]; float rw[ECHUNK];   // 12 VGPRs staging
        int* lh = sh.lh;
        for (int i = t; i < NBUCK; i += BT) lh[i] = 0;
        __syncthreads();
        int base = bid * EPB;
#pragma unroll
        for (int i = 0; i < ECHUNK; ++i) {          // pass 1: load + count
            int k = i * BT + t;
            rd[i] = -1;
            if (k < EPB) {
                int e = base + k;
                rd[i] = dst[e];
                rs[i] = src[e];
                rw[i] = ew[e];
                atomicAdd(&lh[rd[i] >> 6], 1);
            }
        }
        __syncthreads();
        for (int i = t; i < NBUCK; i += BT) {
            int c = lh[i];
            lh[i] = (c > 0) ? atomicAdd(&gcur[i], c) : 0;   // block's run base
        }
        __syncthreads();
#pragma unroll
        for (int i = 0; i < ECHUNK; ++i) {          // pass 2: scatter from regs
            if (rd[i] >= 0) {
                int bkt = rd[i] >> 6;
                int pos = atomicAdd(&lh[bkt], 1);
                if (pos < CAP)
                    binned[(size_t)bkt * CAP + pos] =
                        ((unsigned long long)__float_as_uint(rw[i]) << 32)
                      | ((unsigned)rs[i] << 16) | (unsigned)rd[i];
            }
        }
    } else {
        float (*Ws)[D] = sh.gm.Ws;
        float (*Xs)[D] = sh.gm.Xs;
        for (int k = t; k < D * D; k += BT) Ws[k / D][k % D] = W[k];
        int base = (bid - BINBLK) * 64;
        int r = t >> 6, c = t & 63;                 // r: 0..15
        for (int g = 0; g < 4; ++g) {
            int row = base + g * 16 + r;
            __syncthreads();   // covers Ws staging (g=0) and Xs reuse (g>0)
            Xs[r][c] = (row < N_NODES) ? x[(size_t)row * D + c] : 0.0f;
            __syncthreads();
            float acc = 0.0f;
#pragma unroll
            for (int k = 0; k < D; ++k) acc = fmaf(Xs[r][k], Ws[k][c], acc);
            if (row < N_NODES) hb[(size_t)row * D + c] = f2bf(acc);
        }
    }
}

// one block per bucket: counting-sort to per-node CSR (u32 bf16ew|src) within
// the padded region; fused weighted degree -> dinv; rc = (cnt<<12)|excl
__global__ void k_sortbucket(const unsigned long long* __restrict__ binned,
                             const int* __restrict__ gcur,
                             unsigned* __restrict__ csr,
                             unsigned* __restrict__ rc,
                             float* __restrict__ dinv) {
    __shared__ unsigned long long stage[CAP];   // 12 KB
    __shared__ unsigned long long cw[64];       // (cnt<<40) | fix22 wsum
    __shared__ int off2[64];
    int t = threadIdx.x;
    if (t < 64) cw[t] = 0ULL;
    __syncthreads();
    int b = blockIdx.x;
    size_t beg = (size_t)b * CAP;
    int len = min(gcur[b], CAP);
    for (int k = t; k < len; k += 256) {
        unsigned long long p = binned[beg + k];
        stage[k] = p;
        int dl = (int)(p & 63);
        float w = __uint_as_float((unsigned)(p >> 32));
        atomicAdd(&cw[dl], (1ULL << 40) | (unsigned long long)__float2uint_rn(w * FIXSCALE));
    }
    __syncthreads();
    if (t < 64) {
        int c = (int)(cw[t] >> 40);
        float wfix = (float)(cw[t] & ((1ULL << 40) - 1ULL));
        int inc = wave_incl_scan(c, t);
        int excl = inc - c;
        off2[t] = excl;
        int node = b * 64 + t;
        if (node < N_NODES) {
            rc[node] = ((unsigned)c << 12) | (unsigned)excl;
            dinv[node] = rsqrtf(1.0f + wfix * (1.0f / FIXSCALE));
        }
    }
    __syncthreads();
    for (int k = t; k < len; k += 256) {
        unsigned long long p = stage[k];
        int dl = (int)(p & 63);
        int r = atomicAdd(&off2[dl], 1);
        unsigned short ewb = f2bf(__uint_as_float((unsigned)(p >> 32)));
        csr[beg + r] = ((unsigned)ewb << 16) | (unsigned)((p >> 16) & 0xffffu);
    }
}

// one wave per node, two 32-lane halves processing alternate edges of each
// pair — control flow is WAVE-UNIFORM (shfl always executed with all lanes
// active; per-lane shfl index jp+half is a legal bpermute).
__global__ void k_aggregate(const unsigned short* __restrict__ hb,
                            const float* __restrict__ dinv,
                            const unsigned* __restrict__ rc,
                            const unsigned* __restrict__ csr,
                            const float* __restrict__ bias,
                            float* __restrict__ out) {
    int node = blockIdx.x * 4 + (threadIdx.x >> 6);
    int lane = threadIdx.x & 63;
    if (node >= N_NODES) return;
    int half = lane >> 5;
    int cl = lane & 31;          // column pair: cols 2cl, 2cl+1
    float di = dinv[node];
    unsigned r = rc[node];
    int cnt = (int)(r >> 12);
    size_t beg = (size_t)(node >> 6) * CAP + (r & 0xFFFu);
    float a0 = 0.0f, a1 = 0.0f, p0 = 0.0f, p1 = 0.0f;
    {   // self-loop term, counted once (half 0 lanes)
        unsigned hd = *(const unsigned*)(hb + (size_t)node * D + 2 * cl);
        float m = (half == 0) ? di : 0.0f;
        a0 = m * bf2f((unsigned short)hd);
        a1 = m * bf2f((unsigned short)(hd >> 16));
    }
    for (int b0 = 0; b0 < cnt; b0 += 64) {
        int n = min(64, cnt - b0);
        int my_src = 0;
        float my_ew = 0.0f;
        if (lane < n) {
            unsigned q = csr[beg + b0 + lane];
            my_src = (int)(q & 0xffffu);
            my_ew = bf2f((unsigned short)(q >> 16)) * dinv[my_src];  // L2-resident
        }
        int jp = 0;
        for (; jp + 3 < n; jp += 4) {        // uniform: pairs (jp, jp+1), (jp+2, jp+3)
            int iA = jp + half, iB = jp + 2 + half;
            int sA = __shfl(my_src, iA, 64);
            float eA = __shfl(my_ew, iA, 64);
            int sB = __shfl(my_src, iB, 64);
            float eB = __shfl(my_ew, iB, 64);
            unsigned hA = *(const unsigned*)(hb + (size_t)sA * D + 2 * cl);
            unsigned hB = *(const unsigned*)(hb + (size_t)sB * D + 2 * cl);
            a0 = fmaf(bf2f((unsigned short)hA), eA, a0);
            a1 = fmaf(bf2f((unsigned short)(hA >> 16)), eA, a1);
            p0 = fmaf(bf2f((unsigned short)hB), eB, p0);
            p1 = fmaf(bf2f((unsigned short)(hB >> 16)), eB, p1);
        }
        for (; jp + 1 < n; jp += 2) {        // uniform: one pair
            int iA = jp + half;
            int sA = __shfl(my_src, iA, 64);
            float eA = __shfl(my_ew, iA, 64);
            unsigned hA = *(const unsigned*)(hb + (size_t)sA * D + 2 * cl);
            a0 = fmaf(bf2f((unsigned short)hA), eA, a0);
            a1 = fmaf(bf2f((unsigned short)(hA >> 16)), eA, a1);
        }
        if (jp < n) {                        // lone last edge: uniform shfl, half0 FMA
            int sA = __shfl(my_src, jp, 64);
            float eA = __shfl(my_ew, jp, 64);
            unsigned hA = *(const unsigned*)(hb + (size_t)sA * D + 2 * cl);
            float m = (half == 0) ? eA : 0.0f;
            a0 = fmaf(bf2f((unsigned short)hA), m, a0);
            a1 = fmaf(bf2f((unsigned short)(hA >> 16)), m, a1);
        }
    }
    a0 += p0; a1 += p1;
    a0 += __shfl_xor(a0, 32, 64);            // combine halves
    a1 += __shfl_xor(a1, 32, 64);
    if (half == 0) {
        float v0 = fmaf(di, a0, bias[2 * cl]);
        float v1 = fmaf(di, a1, bias[2 * cl + 1]);
        float2 o;
        o.x = fmaxf(v0, 0.0f);
        o.y = fmaxf(v1, 0.0f);
        *(float2*)(out + (size_t)node * D + 2 * cl) = o;
    }
}

// ---------------- launch ----------------

extern "C" void kernel_launch(void* const* d_in, const int* in_sizes, int n_in,
                              void* d_out, int out_size, void* d_ws, size_t ws_size,
                              hipStream_t stream) {
    const float* x  = (const float*)d_in[0];
    const int*   ei = (const int*)d_in[1];    // [2, E] row-major, int32
    const float* ew = (const float*)d_in[2];
    const float* W  = (const float*)d_in[3];
    const float* b  = (const float*)d_in[4];
    float* out = (float*)d_out;

    const int* src = ei;
    const int* dst = ei + N_EDGES;

    // workspace layout (8B-aligned first)
    unsigned long long* binned = (unsigned long long*)d_ws;          // NBUCK*CAP u64 (9.6MB)
    unsigned* csr      = (unsigned*)(binned + (size_t)NBUCK * CAP);  // NBUCK*CAP u32 (4.8MB)
    int*   gcur        = (int*)(csr + (size_t)NBUCK * CAP);          // 1024
    unsigned* rc       = (unsigned*)(gcur + 1024);                   // 50048
    float* dinv        = (float*)(rc + 50048);                       // 50048
    unsigned short* hb = (unsigned short*)(dinv + 50048);            // N*D bf16 (6.4MB)

    k_zero<<<4, dim3(256), 0, stream>>>(gcur);
    k_bin_gemm<<<BINBLK + GEMMBLK64, dim3(BT), 0, stream>>>(src, dst, ew, gcur,
                                                            binned, x, W, hb);
    k_sortbucket<<<NBUCK, dim3(256), 0, stream>>>(binned, gcur, csr, rc, dinv);
    k_aggregate<<<(N_NODES + 3) / 4, dim3(256), 0, stream>>>(hb, dinv, rc, csr, b, out);
}

// Round 22
// 72.268 us; speedup vs baseline: 1.2412x; 1.1838x over previous
//
#include <hip/hip_runtime.h>

#define N_NODES 50000
#define N_EDGES 800000
#define D 64
#define NBUCK 782            // ceil(50000/64) buckets of 64 dst nodes
#define BINBLK 256           // bin blocks (1 per CU): runs of ~4 edges
#define EPB 3125             // edges per bin block (256*3125 = 800000)
#define ECHUNK 13            // ceil(3125/256)
#define GEMMBLK ((N_NODES + 15) / 16)   // 3125 gemm tiles, 16 rows each
#define CAP 1536             // bucket capacity (mean 1024 + 16 sigma)
#define FIXSCALE 4194304.0f  // 2^22 fixed-point for weighted degree

// ---------------- helpers ----------------

__device__ inline unsigned short f2bf(float f) {
    unsigned u = __float_as_uint(f);
    unsigned r = (u + 0x7FFFu + ((u >> 16) & 1u)) >> 16;   // RNE
    return (unsigned short)r;
}
__device__ inline float bf2f(unsigned short h) {
    return __uint_as_float(((unsigned)h) << 16);
}
__device__ inline int wave_incl_scan(int v, int lane) {
#pragma unroll
    for (int off = 1; off < 64; off <<= 1) {
        int n = __shfl_up(v, off, 64);
        if (lane >= off) v += n;
    }
    return v;
}

// ---------------- kernels ----------------

__global__ void k_zero(int* __restrict__ gcur) {
    int i = blockIdx.x * blockDim.x + threadIdx.x;
    if (i < NBUCK) gcur[i] = 0;
}

// Fused (R17-proven): blocks [0,BINBLK) bin edges into bucket regions;
// blocks [BINBLK,..) compute hb = bf16(x @ W).
union ShU {
    int lh[NBUCK];                                   // bin: 3.1 KB
    struct { float Ws[D][D]; float Xs[4][D]; } gm;   // 17.4 KB
};
__global__ __launch_bounds__(256) void k_bin_gemm(
        const int* __restrict__ src, const int* __restrict__ dst,
        const float* __restrict__ ew,
        int* __restrict__ gcur, unsigned long long* __restrict__ binned,
        const float* __restrict__ x, const float* __restrict__ W,
        unsigned short* __restrict__ hb) {
    __shared__ ShU sh;
    int t = threadIdx.x;
    if (blockIdx.x < BINBLK) {
        int rd[ECHUNK]; int rs[ECHUNK]; float rw[ECHUNK];
        int* lh = sh.lh;
        for (int i = t; i < NBUCK; i += 256) lh[i] = 0;
        __syncthreads();
        int base = blockIdx.x * EPB;
#pragma unroll
        for (int i = 0; i < ECHUNK; ++i) {          // pass 1: load + count
            int k = i * 256 + t;
            rd[i] = -1;
            if (k < EPB) {
                int e = base + k;
                rd[i] = dst[e];
                rs[i] = src[e];
                rw[i] = ew[e];
                atomicAdd(&lh[rd[i] >> 6], 1);
            }
        }
        __syncthreads();
        for (int i = t; i < NBUCK; i += 256) {
            int c = lh[i];
            lh[i] = (c > 0) ? atomicAdd(&gcur[i], c) : 0;   // block's run base
        }
        __syncthreads();
#pragma unroll
        for (int i = 0; i < ECHUNK; ++i) {          // pass 2: scatter from regs
            if (rd[i] >= 0) {
                int bkt = rd[i] >> 6;
                int pos = atomicAdd(&lh[bkt], 1);
                if (pos < CAP)
                    binned[(size_t)bkt * CAP + pos] =
                        ((unsigned long long)__float_as_uint(rw[i]) << 32)
                      | ((unsigned)rs[i] << 16) | (unsigned)rd[i];
            }
        }
    } else {
        float (*Ws)[D] = sh.gm.Ws;
        float (*Xs)[D] = sh.gm.Xs;
        for (int k = t; k < D * D; k += 256) Ws[k / D][k % D] = W[k];
        int base = (blockIdx.x - BINBLK) * 16;
        int r = t >> 6, c = t & 63;
        for (int g = 0; g < 4; ++g) {
            int row = base + g * 4 + r;
            __syncthreads();   // covers Ws staging (g=0) and Xs reuse (g>0)
            Xs[r][c] = (row < N_NODES) ? x[(size_t)row * D + c] : 0.0f;
            __syncthreads();
            float acc = 0.0f;
#pragma unroll
            for (int k = 0; k < D; ++k) acc = fmaf(Xs[r][k], Ws[k][c], acc);
            if (row < N_NODES) hb[(size_t)row * D + c] = f2bf(acc);
        }
    }
}

// one block per bucket (R17-proven): counting-sort to per-node CSR
// (u32 bf16ew|src); fused weighted degree -> dinv; rc = (cnt<<12)|excl
__global__ void k_sortbucket(const unsigned long long* __restrict__ binned,
                             const int* __restrict__ gcur,
                             unsigned* __restrict__ csr,
                             unsigned* __restrict__ rc,
                             float* __restrict__ dinv) {
    __shared__ unsigned long long stage[CAP];   // 12 KB
    __shared__ unsigned long long cw[64];       // (cnt<<40) | fix22 wsum
    __shared__ int off2[64];
    int t = threadIdx.x;
    if (t < 64) cw[t] = 0ULL;
    __syncthreads();
    int b = blockIdx.x;
    size_t beg = (size_t)b * CAP;
    int len = min(gcur[b], CAP);
    for (int k = t; k < len; k += 256) {
        unsigned long long p = binned[beg + k];
        stage[k] = p;
        int dl = (int)(p & 63);
        float w = __uint_as_float((unsigned)(p >> 32));
        atomicAdd(&cw[dl], (1ULL << 40) | (unsigned long long)__float2uint_rn(w * FIXSCALE));
    }
    __syncthreads();
    if (t < 64) {
        int c = (int)(cw[t] >> 40);
        float wfix = (float)(cw[t] & ((1ULL << 40) - 1ULL));
        int inc = wave_incl_scan(c, t);
        int excl = inc - c;
        off2[t] = excl;
        int node = b * 64 + t;
        if (node < N_NODES) {
            rc[node] = ((unsigned)c << 12) | (unsigned)excl;
            dinv[node] = rsqrtf(1.0f + wfix * (1.0f / FIXSCALE));
        }
    }
    __syncthreads();
    for (int k = t; k < len; k += 256) {
        unsigned long long p = stage[k];
        int dl = (int)(p & 63);
        int r = atomicAdd(&off2[dl], 1);
        unsigned short ewb = f2bf(__uint_as_float((unsigned)(p >> 32)));
        csr[beg + r] = ((unsigned)ewb << 16) | (unsigned)((p >> 16) & 0xffffu);
    }
}

// one wave per node, FOUR 16-lane quarters; quarter q handles edge jp+q.
// Each lane loads u64 = 4 bf16 cols. Control flow wave-uniform: main loop
// runs only full 8-edge groups (all shfl indices < n provably); single
// masked tail step (multiplier zeroed for invalid edges).
__global__ void k_aggregate(const unsigned short* __restrict__ hb,
                            const float* __restrict__ dinv,
                            const unsigned* __restrict__ rc,
                            const unsigned* __restrict__ csr,
                            const float* __restrict__ bias,
                            float* __restrict__ out) {
    int node = blockIdx.x * 4 + (threadIdx.x >> 6);
    int lane = threadIdx.x & 63;
    if (node >= N_NODES) return;
    int quarter = lane >> 4;     // 0..3
    int cq = lane & 15;          // col group: cols 4cq..4cq+3
    float di = dinv[node];
    unsigned r = rc[node];
    int cnt = (int)(r >> 12);
    size_t beg = (size_t)(node >> 6) * CAP + (r & 0xFFFu);
    float a0, a1, a2, a3;
    {   // self-loop term, counted once (quarter 0)
        unsigned long long hd =
            *(const unsigned long long*)(hb + (size_t)node * D + 4 * cq);
        float m = (quarter == 0) ? di : 0.0f;
        a0 = m * bf2f((unsigned short)hd);
        a1 = m * bf2f((unsigned short)(hd >> 16));
        a2 = m * bf2f((unsigned short)(hd >> 32));
        a3 = m * bf2f((unsigned short)(hd >> 48));
    }
    float p0 = 0.0f, p1 = 0.0f, p2 = 0.0f, p3 = 0.0f;
    for (int b0 = 0; b0 < cnt; b0 += 64) {
        int n = min(64, cnt - b0);
        int my_src = 0;
        float my_ew = 0.0f;
        if (lane < n) {
            unsigned q = csr[beg + b0 + lane];
            my_src = (int)(q & 0xffffu);
            my_ew = bf2f((unsigned short)(q >> 16)) * dinv[my_src];  // L2-resident
        }
        int jp = 0;
        for (; jp + 8 <= n; jp += 8) {   // full groups: iA,iB < n guaranteed
            int iA = jp + quarter, iB = iA + 4;
            int sA = __shfl(my_src, iA, 64);
            float eA = __shfl(my_ew, iA, 64);
            int sB = __shfl(my_src, iB, 64);
            float eB = __shfl(my_ew, iB, 64);
            unsigned long long hA =
                *(const unsigned long long*)(hb + (size_t)sA * D + 4 * cq);
            unsigned long long hB =
                *(const unsigned long long*)(hb + (size_t)sB * D + 4 * cq);
            a0 = fmaf(bf2f((unsigned short)hA), eA, a0);
            a1 = fmaf(bf2f((unsigned short)(hA >> 16)), eA, a1);
            a2 = fmaf(bf2f((unsigned short)(hA >> 32)), eA, a2);
            a3 = fmaf(bf2f((unsigned short)(hA >> 48)), eA, a3);
            p0 = fmaf(bf2f((unsigned short)hB), eB, p0);
            p1 = fmaf(bf2f((unsigned short)(hB >> 16)), eB, p1);
            p2 = fmaf(bf2f((unsigned short)(hB >> 32)), eB, p2);
            p3 = fmaf(bf2f((unsigned short)(hB >> 48)), eB, p3);
        }
        if (jp < n) {                    // masked tail (≤7 edges), uniform
            int iA = jp + quarter, iB = iA + 4;   // iB ≤ 63 (jp ≤ 56)
            int sA = __shfl(my_src, iA, 64);
            float eA = __shfl(my_ew, iA, 64);
            int sB = __shfl(my_src, iB, 64);
            float eB = __shfl(my_ew, iB, 64);
            eA = (iA < n) ? eA : 0.0f;   // masked lanes had my_ew=0 anyway
            eB = (iB < n) ? eB : 0.0f;
            unsigned long long hA =
                *(const unsigned long long*)(hb + (size_t)sA * D + 4 * cq);
            unsigned long long hB =
                *(const unsigned long long*)(hb + (size_t)sB * D + 4 * cq);
            a0 = fmaf(bf2f((unsigned short)hA), eA, a0);
            a1 = fmaf(bf2f((unsigned short)(hA >> 16)), eA, a1);
            a2 = fmaf(bf2f((unsigned short)(hA >> 32)), eA, a2);
            a3 = fmaf(bf2f((unsigned short)(hA >> 48)), eA, a3);
            p0 = fmaf(bf2f((unsigned short)hB), eB, p0);
            p1 = fmaf(bf2f((unsigned short)(hB >> 16)), eB, p1);
            p2 = fmaf(bf2f((unsigned short)(hB >> 32)), eB, p2);
            p3 = fmaf(bf2f((unsigned short)(hB >> 48)), eB, p3);
        }
    }
    a0 += p0; a1 += p1; a2 += p2; a3 += p3;
    a0 += __shfl_xor(a0, 16, 64); a0 += __shfl_xor(a0, 32, 64);
    a1 += __shfl_xor(a1, 16, 64); a1 += __shfl_xor(a1, 32, 64);
    a2 += __shfl_xor(a2, 16, 64); a2 += __shfl_xor(a2, 32, 64);
    a3 += __shfl_xor(a3, 16, 64); a3 += __shfl_xor(a3, 32, 64);
    if (quarter == 0) {
        float4 o;
        o.x = fmaxf(fmaf(di, a0, bias[4 * cq + 0]), 0.0f);
        o.y = fmaxf(fmaf(di, a1, bias[4 * cq + 1]), 0.0f);
        o.z = fmaxf(fmaf(di, a2, bias[4 * cq + 2]), 0.0f);
        o.w = fmaxf(fmaf(di, a3, bias[4 * cq + 3]), 0.0f);
        *(float4*)(out + (size_t)node * D + 4 * cq) = o;
    }
}

// ---------------- launch ----------------

extern "C" void kernel_launch(void* const* d_in, const int* in_sizes, int n_in,
                              void* d_out, int out_size, void* d_ws, size_t ws_size,
                              hipStream_t stream) {
    const float* x  = (const float*)d_in[0];
    const int*   ei = (const int*)d_in[1];    // [2, E] row-major, int32
    const float* ew = (const float*)d_in[2];
    const float* W  = (const float*)d_in[3];
    const float* b  = (const float*)d_in[4];
    float* out = (float*)d_out;

    const int* src = ei;
    const int* dst = ei + N_EDGES;

    // workspace layout (8B-aligned first)
    unsigned long long* binned = (unsigned long long*)d_ws;          // NBUCK*CAP u64 (9.6MB)
    unsigned* csr      = (unsigned*)(binned + (size_t)NBUCK * CAP);  // NBUCK*CAP u32 (4.8MB)
    int*   gcur        = (int*)(csr + (size_t)NBUCK * CAP);          // 1024
    unsigned* rc       = (unsigned*)(gcur + 1024);                   // 50048
    float* dinv        = (float*)(rc + 50048);                       // 50048
    unsigned short* hb = (unsigned short*)(dinv + 50048);            // N*D bf16 (6.4MB)

    dim3 blk(256);
    k_zero<<<4, blk, 0, stream>>>(gcur);
    k_bin_gemm<<<BINBLK + GEMMBLK, blk, 0, stream>>>(src, dst, ew, gcur, binned,
                                                     x, W, hb);
    k_sortbucket<<<NBUCK, blk, 0, stream>>>(binned, gcur, csr, rc, dinv);
    k_aggregate<<<(N_NODES + 3) / 4, blk, 0, stream>>>(hb, dinv, rc, csr, b, out);
}